// Round 1
// baseline (20285.893 us; speedup 1.0000x reference)
//
#include <hip/hip_runtime.h>

// ---------------------------------------------------------------------------
// Two-layer tanh RNN, persistent-register chain kernels.
// B=64, T=512, L=2, H=512, I=128, W_OUT=32. All inputs fp32.
//
// Phases (all on `stream`, ordered):
//   1) init_pack  : pack [W_in | W_hh] as f16 pairs in per-lane order; zero cnts
//   2) chain<128,true>  : layer-0 recurrence, writes h0 sequence (f16 pairs)
//   3) chain<512,false> : layer-1 recurrence (consumes h0 seq), writes final h1
//   4) fc_kernel  : out = h1 @ fc_w^T + fc_b
//
// Chain kernel: G=8 workgroups per batch element (512 WGs, 2/CU, co-resident
// by __launch_bounds__(256,2)). Lane owns row r = wg*64 + L/4 and k-chunk
// c = L&3 of the concatenated K (640 or 1024); weights live in VGPRs as f16
// pairs; h broadcast from LDS; v_dot2_f32_f16 accumulate in fp32.
// Cross-WG h exchange: agent-scope (sc1) atomics + per-batch monotonic
// release counter, double-buffered by step parity (overwrite-race-free).
// ---------------------------------------------------------------------------

#define TSTEPS 512
#define BATCH  64

typedef _Float16 half2v __attribute__((ext_vector_type(2)));

__device__ __forceinline__ unsigned pack2(float a, float b) {
    _Float16 fa = (_Float16)a, fb = (_Float16)b;
    unsigned short ua = __builtin_bit_cast(unsigned short, fa);
    unsigned short ub = __builtin_bit_cast(unsigned short, fb);
    return (unsigned)ua | ((unsigned)ub << 16);
}

__device__ __forceinline__ float dot2acc(unsigned w, unsigned h, float acc) {
#if __has_builtin(__builtin_amdgcn_fdot2)
    return __builtin_amdgcn_fdot2(__builtin_bit_cast(half2v, w),
                                  __builtin_bit_cast(half2v, h), acc, false);
#else
    half2v wv = __builtin_bit_cast(half2v, w);
    half2v hv = __builtin_bit_cast(half2v, h);
    acc = fmaf((float)wv.x, (float)hv.x, acc);
    return fmaf((float)wv.y, (float)hv.y, acc);
#endif
}

// N0/N1: packed-weight element counts. Layout [wg<8][j<P][lane<256].
#define N0 (8 * 80 * 256)    // layer0: P=80  (K=640)
#define N1 (8 * 128 * 256)   // layer1: P=128 (K=1024)

__global__ void init_pack(const float* __restrict__ Wih0, const float* __restrict__ Whh0,
                          const float* __restrict__ Wih1, const float* __restrict__ Whh1,
                          unsigned* __restrict__ wp0, unsigned* __restrict__ wp1,
                          unsigned* __restrict__ cnts) {
    int gid = blockIdx.x * 256 + threadIdx.x;
    if (gid < 128) cnts[gid] = 0u;   // cnt0[64] + cnt1[64]
    if (gid < N0) {
        int L = gid & 255; int j = (gid >> 8) % 80; int wg = (gid >> 8) / 80;
        int r = wg * 64 + (L >> 2); int c = L & 3; int k = c * 160 + 2 * j;
        float w0 = (k < 128) ? Wih0[r * 128 + k]     : Whh0[r * 512 + (k - 128)];
        float w1 = (k + 1 < 128) ? Wih0[r * 128 + k + 1] : Whh0[r * 512 + (k - 127)];
        wp0[gid] = pack2(w0, w1);
    } else {
        int g2 = gid - N0;
        if (g2 < N1) {
            int L = g2 & 255; int j = (g2 >> 8) % 128; int wg = (g2 >> 8) / 128;
            int r = wg * 64 + (L >> 2); int c = L & 3; int k = c * 256 + 2 * j;
            float w0 = (k < 512) ? Wih1[r * 512 + k]     : Whh1[r * 512 + (k - 512)];
            float w1 = (k + 1 < 512) ? Wih1[r * 512 + k + 1] : Whh1[r * 512 + (k - 511)];
            wp1[g2] = pack2(w0, w1);
        }
    }
}

// KIN = extra (non-recurrent) input width: 128 (x) for layer0, 512 (h0) for layer1.
// WRITE_SEQ: layer0 writes h sequence; layer1 writes only final h.
template <int KIN, bool WRITE_SEQ>
__global__ __launch_bounds__(256, 2)
void chain_kernel(const float* __restrict__ x, const unsigned* __restrict__ seq_in,
                  unsigned* __restrict__ seq_out, const unsigned* __restrict__ wpack,
                  const float* __restrict__ bih, const float* __restrict__ bhh,
                  const float* __restrict__ noise, unsigned* __restrict__ hbuf,
                  unsigned* __restrict__ cnt, float* __restrict__ h1fin) {
    constexpr int KT = KIN + 512;        // total K (concat input | recurrent)
    constexpr int P  = KT / 8;           // f16-pairs per lane (4 chunks x 64 rows)
    constexpr int CH = P + 4;            // LDS chunk stride in words (bank-spread, keeps 16B align)
    constexpr int G  = 8;                // WGs per batch element
    constexpr int LAYER = WRITE_SEQ ? 0 : 1;

    const int b  = blockIdx.x & 63;      // group = batch element; WGs of a group
    const int wg = blockIdx.x >> 6;      //   are 64 apart -> same XCD under round-robin
    const int L  = threadIdx.x;
    const int c  = L & 3;                // k-chunk
    const int r  = wg * 64 + (L >> 2);   // owned output row

    // --- persistent weights in VGPRs ---
    unsigned wreg[P];
#pragma unroll
    for (int j = 0; j < P; ++j) wreg[j] = wpack[(wg * P + j) * 256 + L];

    const float cb = bih[r] + bhh[r];
    const float* nzp = noise + ((size_t)b * TSTEPS * 2 + LAYER) * 512 + r; // stride 1024/step

    __shared__ __align__(16) unsigned hv[4 * CH];
    for (int i = L; i < 4 * CH; i += 256) hv[i] = 0u;   // h-part starts at zero (h[-1]=0)
    __syncthreads();
    // t=0 input part
    if constexpr (KIN == 128) {
        if (L < 64) {
            float2 xf = *(const float2*)(x + (size_t)b * 65536 + 2 * L);
            hv[L] = pack2(xf.x, xf.y);                  // pair p=L<80 -> chunk0
        }
    } else {
        unsigned v = seq_in[(size_t)b * TSTEPS * 256 + L];
        hv[(L >> 7) * CH + (L & 127)] = v;              // pairs 0..255 -> chunks 0,1
    }
    __syncthreads();

    long spin_budget = 200000000L;   // bail out instead of hanging on any sync bug

    for (int t = 0; t < TSTEPS; ++t) {
        const float nz = nzp[(size_t)t * 1024];
        float a0 = 0.f, a1 = 0.f, a2 = 0.f, a3 = 0.f;
        const uint4* hq = (const uint4*)(&hv[c * CH]);
#pragma unroll
        for (int jj = 0; jj < P / 4; ++jj) {
            uint4 hp = hq[jj];
            a0 = dot2acc(wreg[4 * jj + 0], hp.x, a0);
            a1 = dot2acc(wreg[4 * jj + 1], hp.y, a1);
            a2 = dot2acc(wreg[4 * jj + 2], hp.z, a2);
            a3 = dot2acc(wreg[4 * jj + 3], hp.w, a3);
        }
        float acc = (a0 + a1) + (a2 + a3);
        acc += __shfl_xor(acc, 1);       // combine 4 k-chunks of this row
        acc += __shfl_xor(acc, 2);
        const float hnew = tanhf(acc + cb + nz);
        const float hnb  = __shfl_down(hnew, 4);   // row r+1's value (same chunk lane)
        const bool last  = (t == TSTEPS - 1);

        if constexpr (!WRITE_SEQ) {
            if (last && c == 0)
                __hip_atomic_store(&h1fin[b * 512 + r], hnew,
                                   __ATOMIC_RELAXED, __HIP_MEMORY_SCOPE_AGENT);
        }
        if ((L & 7) == 0) {              // one writer per row-pair
            unsigned pv = pack2(hnew, hnb);
            if constexpr (WRITE_SEQ)
                __hip_atomic_store(&seq_out[((size_t)b * TSTEPS + t) * 256 + (r >> 1)], pv,
                                   __ATOMIC_RELAXED, __HIP_MEMORY_SCOPE_AGENT);
            if (!last)
                __hip_atomic_store(&hbuf[(t & 1) * (BATCH * 256) + b * 256 + (r >> 1)], pv,
                                   __ATOMIC_RELAXED, __HIP_MEMORY_SCOPE_AGENT);
        }
        if (last) break;                 // uniform across all WGs

        __syncthreads();                 // drains vmem (stores complete) before flag
        if (L == 0)
            __hip_atomic_fetch_add(cnt + b, 1u, __ATOMIC_RELEASE, __HIP_MEMORY_SCOPE_AGENT);

        // prefetch next step's input part while we wait on peers
        float2 xf; unsigned nv = 0u;
        if constexpr (KIN == 128) {
            if (L < 64)
                xf = *(const float2*)(x + (size_t)b * 65536 + (size_t)(t + 1) * 128 + 2 * L);
        } else {
            nv = seq_in[((size_t)b * TSTEPS + (t + 1)) * 256 + L];
        }

        if (L == 0) {
            const unsigned target = (unsigned)(t + 1) * G;
            while (__hip_atomic_load(cnt + b, __ATOMIC_RELAXED, __HIP_MEMORY_SCOPE_AGENT) < target) {
                if (--spin_budget < 0) break;
            }
            __builtin_amdgcn_fence(__ATOMIC_ACQUIRE, "agent");
        }
        __syncthreads();

        // gather full h (all 256 pairs, incl. our own) and scatter into LDS chunks
        unsigned hb = __hip_atomic_load(&hbuf[(t & 1) * (BATCH * 256) + b * 256 + L],
                                        __ATOMIC_RELAXED, __HIP_MEMORY_SCOPE_AGENT);
        {
            int p = (KIN / 2) + L;                       // recurrent-part pair index
            hv[(p / P) * CH + (p % P)] = hb;
            if constexpr (KIN == 128) {
                if (L < 64) hv[L] = pack2(xf.x, xf.y);
            } else {
                hv[(L >> 7) * CH + (L & 127)] = nv;
            }
        }
        __syncthreads();
    }
}

__global__ void fc_kernel(const float* __restrict__ h1f, const float* __restrict__ fcw,
                          const float* __restrict__ fcb, float* __restrict__ out) {
    const int b = blockIdx.x, tid = threadIdx.x;
    __shared__ float hs[512];
    __shared__ float part[256];
    hs[tid]       = h1f[b * 512 + tid];
    hs[256 + tid] = h1f[b * 512 + 256 + tid];
    __syncthreads();
    const int w = tid & 31, seg = tid >> 5;      // 8 k-segments x 32 outputs
    const float* wr = fcw + w * 512 + seg * 64;
    const float* hr = hs + seg * 64;
    float a = 0.f;
#pragma unroll
    for (int k = 0; k < 64; ++k) a = fmaf(wr[k], hr[k], a);
    part[tid] = a;
    __syncthreads();
    if (tid < 32) {
        float s = fcb[tid];
#pragma unroll
        for (int sgi = 0; sgi < 8; ++sgi) s += part[sgi * 32 + tid];
        out[b * 32 + tid] = s;
    }
}

extern "C" void kernel_launch(void* const* d_in, const int* in_sizes, int n_in,
                              void* d_out, int out_size, void* d_ws, size_t ws_size,
                              hipStream_t stream) {
    const float* x     = (const float*)d_in[0];
    const float* noise = (const float*)d_in[1];
    const float* Wih0  = (const float*)d_in[2];
    const float* Wih1  = (const float*)d_in[3];
    const float* Whh0  = (const float*)d_in[4];
    const float* Whh1  = (const float*)d_in[5];
    const float* bih0  = (const float*)d_in[6];
    const float* bih1  = (const float*)d_in[7];
    const float* bhh0  = (const float*)d_in[8];
    const float* bhh1  = (const float*)d_in[9];
    const float* fcw   = (const float*)d_in[10];
    const float* fcb   = (const float*)d_in[11];
    float* out = (float*)d_out;

    char* ws = (char*)d_ws;
    size_t o = 0;
    unsigned* wp0  = (unsigned*)(ws + o); o += (size_t)N0 * 4;            // 640 KB
    unsigned* wp1  = (unsigned*)(ws + o); o += (size_t)N1 * 4;            // 1 MB
    unsigned* cnts = (unsigned*)(ws + o); o += 512;                       // cnt0|cnt1
    unsigned* hb0  = (unsigned*)(ws + o); o += (size_t)2 * BATCH * 256 * 4;
    unsigned* hb1  = (unsigned*)(ws + o); o += (size_t)2 * BATCH * 256 * 4;
    float*    h1f  = (float*)(ws + o);    o += (size_t)BATCH * 512 * 4;
    unsigned* seq  = (unsigned*)(ws + o); o += (size_t)BATCH * TSTEPS * 256 * 4; // 33.5 MB

    const int initBlocks = (N0 + N1 + 255) / 256;
    init_pack<<<initBlocks, 256, 0, stream>>>(Wih0, Whh0, Wih1, Whh1, wp0, wp1, cnts);
    chain_kernel<128, true ><<<512, 256, 0, stream>>>(x, nullptr, seq, wp0, bih0, bhh0,
                                                      noise, hb0, cnts, nullptr);
    chain_kernel<512, false><<<512, 256, 0, stream>>>(nullptr, seq, nullptr, wp1, bih1, bhh1,
                                                      noise, hb1, cnts + 64, h1f);
    fc_kernel<<<BATCH, 256, 0, stream>>>(h1f, fcw, fcb, out);
}

// Round 2
// 2172.682 us; speedup vs baseline: 9.3368x; 9.3368x over previous
//
#include <hip/hip_runtime.h>

// ---------------------------------------------------------------------------
// Two-layer tanh RNN, persistent-register chain kernels — fence-free sync.
// B=64, T=512, L=2, H=512, I=128, W_OUT=32. All inputs fp32.
//
//   1) init_pack        : pack [W_in | W_hh] as f16 pairs in per-lane order
//   2) chain<128,true>  : layer-0 recurrence, writes h0 sequence (f16 pairs)
//   3) chain<512,false> : layer-1 recurrence, writes final h1
//   4) fc_kernel        : out = h1 @ fc_w^T + fc_b
//
// Chain kernel: 8 WGs x 256 per batch element (512 WGs, 2/CU co-resident).
// Lane owns row r = wg*64 + L/4 and k-chunk c = L&3; weights pinned in
// VGPRs via asm; h broadcast from LDS; v_dot2_f32_f16 fp32 accumulate.
// Cross-WG exchange: 64-bit {tag|f16pair} atoms, RELAXED agent scope,
// double-buffered by step parity. NO fences (no buffer_inv/wbl2 per step),
// no counter — each lane polls its own word.
// ---------------------------------------------------------------------------

#define TSTEPS 512
#define BATCH  64

typedef _Float16 half2v __attribute__((ext_vector_type(2)));

__device__ __forceinline__ unsigned pack2(float a, float b) {
    _Float16 fa = (_Float16)a, fb = (_Float16)b;
    unsigned short ua = __builtin_bit_cast(unsigned short, fa);
    unsigned short ub = __builtin_bit_cast(unsigned short, fb);
    return (unsigned)ua | ((unsigned)ub << 16);
}

__device__ __forceinline__ float dot2acc(unsigned w, unsigned h, float acc) {
#if __has_builtin(__builtin_amdgcn_fdot2)
    return __builtin_amdgcn_fdot2(__builtin_bit_cast(half2v, w),
                                  __builtin_bit_cast(half2v, h), acc, false);
#else
    half2v wv = __builtin_bit_cast(half2v, w);
    half2v hv = __builtin_bit_cast(half2v, h);
    acc = fmaf((float)wv.x, (float)hv.x, acc);
    return fmaf((float)wv.y, (float)hv.y, acc);
#endif
}

// N0/N1: packed-weight element counts. Layout [wg<8][j<P][lane<256].
#define N0 (8 * 80 * 256)    // layer0: P=80  (K=640)
#define N1 (8 * 128 * 256)   // layer1: P=128 (K=1024)

__global__ void init_pack(const float* __restrict__ Wih0, const float* __restrict__ Whh0,
                          const float* __restrict__ Wih1, const float* __restrict__ Whh1,
                          unsigned* __restrict__ wp0, unsigned* __restrict__ wp1) {
    int gid = blockIdx.x * 256 + threadIdx.x;
    if (gid < N0) {
        int L = gid & 255; int j = (gid >> 8) % 80; int wg = (gid >> 8) / 80;
        int r = wg * 64 + (L >> 2); int c = L & 3; int k = c * 160 + 2 * j;
        float w0 = (k < 128) ? Wih0[r * 128 + k]     : Whh0[r * 512 + (k - 128)];
        float w1 = (k + 1 < 128) ? Wih0[r * 128 + k + 1] : Whh0[r * 512 + (k - 127)];
        wp0[gid] = pack2(w0, w1);
    } else {
        int g2 = gid - N0;
        if (g2 < N1) {
            int L = g2 & 255; int j = (g2 >> 8) % 128; int wg = (g2 >> 8) / 128;
            int r = wg * 64 + (L >> 2); int c = L & 3; int k = c * 256 + 2 * j;
            float w0 = (k < 512) ? Wih1[r * 512 + k]     : Whh1[r * 512 + (k - 512)];
            float w1 = (k + 1 < 512) ? Wih1[r * 512 + k + 1] : Whh1[r * 512 + (k - 511)];
            wp1[g2] = pack2(w0, w1);
        }
    }
}

// KIN = non-recurrent input width: 128 (x) for layer0, 512 (h0) for layer1.
template <int KIN, bool WRITE_SEQ>
__global__ __launch_bounds__(256, 2)
void chain_kernel(const float* __restrict__ x, const unsigned* __restrict__ seq_in,
                  unsigned* __restrict__ seq_out, const unsigned* __restrict__ wpack,
                  const float* __restrict__ bih, const float* __restrict__ bhh,
                  const float* __restrict__ noise,
                  unsigned long long* __restrict__ hbuf,   // 2 slots x BATCH x 256
                  float* __restrict__ h1fin) {
    constexpr int KT = KIN + 512;
    constexpr int P  = KT / 8;           // f16-pairs per lane
    constexpr int CH = P + 4;            // LDS chunk stride (bank-spread, 16B-align ok)
    constexpr int LAYER = WRITE_SEQ ? 0 : 1;

    const int b  = blockIdx.x & 63;      // batch element; 8 WGs of a batch are
    const int wg = blockIdx.x >> 6;      //   64 apart -> same XCD (rr % 8)
    const int L  = threadIdx.x;
    const int c  = L & 3;                // k-chunk
    const int r  = wg * 64 + (L >> 2);   // owned output row

    // --- persistent weights, pinned in the register file ---
    unsigned wreg[P];
#pragma unroll
    for (int j = 0; j < P; ++j) {
        wreg[j] = wpack[(wg * P + j) * 256 + L];
        asm volatile("" : "+v"(wreg[j]));     // opaque: cannot remat/sink the load
    }

    const float cb = bih[r] + bhh[r];
    const float* nzp = noise + ((size_t)b * TSTEPS * 2 + LAYER) * 512 + r;

    __shared__ __align__(16) unsigned hv[4 * CH];
    for (int i = L; i < 4 * CH; i += 256) hv[i] = 0u;   // h[-1] = 0
    __syncthreads();
    if constexpr (KIN == 128) {
        if (L < 64) {
            float2 xf = *(const float2*)(x + (size_t)b * 65536 + 2 * L);
            hv[L] = pack2(xf.x, xf.y);
        }
    } else {
        unsigned v = seq_in[(size_t)b * TSTEPS * 256 + L];
        hv[(L >> 7) * CH + (L & 127)] = v;
    }
    __syncthreads();

    float nz_cur = nzp[0];
    long budget = 400000000L;            // hang-bailout only

    for (int t = 0; t < TSTEPS; ++t) {
        float a0 = 0.f, a1 = 0.f, a2 = 0.f, a3 = 0.f;
        const uint4* hq = (const uint4*)(&hv[c * CH]);
#pragma unroll
        for (int jj = 0; jj < P / 4; ++jj) {
            uint4 hp = hq[jj];
            a0 = dot2acc(wreg[4 * jj + 0], hp.x, a0);
            a1 = dot2acc(wreg[4 * jj + 1], hp.y, a1);
            a2 = dot2acc(wreg[4 * jj + 2], hp.z, a2);
            a3 = dot2acc(wreg[4 * jj + 3], hp.w, a3);
        }
        float acc = (a0 + a1) + (a2 + a3);
        acc += __shfl_xor(acc, 1);
        acc += __shfl_xor(acc, 2);
        const float hnew = tanhf(acc + cb + nz_cur);
        const float hnb  = __shfl_down(hnew, 4);   // row r+1 (same chunk)
        const bool last  = (t == TSTEPS - 1);

        if constexpr (!WRITE_SEQ) {
            if (last && c == 0) h1fin[b * 512 + r] = hnew;
        }
        if ((L & 7) == 0) {              // one writer per row-pair
            unsigned pv = pack2(hnew, hnb);
            if constexpr (WRITE_SEQ)
                seq_out[((size_t)b * TSTEPS + t) * 256 + (r >> 1)] = pv;
            if (!last) {
                unsigned long long atom =
                    ((unsigned long long)(unsigned)(t + 1) << 32) | (unsigned long long)pv;
                __hip_atomic_store(&hbuf[(size_t)(t & 1) * (BATCH * 256) + b * 256 + (r >> 1)],
                                   atom, __ATOMIC_RELAXED, __HIP_MEMORY_SCOPE_AGENT);
            }
        }
        if (last) break;                 // uniform across all WGs

        // prefetch next step's inputs (independent of the sync)
        float2 xf; unsigned nv = 0u;
        if constexpr (KIN == 128) {
            if (L < 64)
                xf = *(const float2*)(x + (size_t)b * 65536 + (size_t)(t + 1) * 128 + 2 * L);
        } else {
            nv = seq_in[((size_t)b * TSTEPS + (t + 1)) * 256 + L];
        }
        float nz_nxt = nzp[(size_t)(t + 1) * 1024];

        __syncthreads();                 // all hv reads of this step done

        // each lane polls its own tagged word — data+tag in one 64-bit atom
        unsigned long long v;
        unsigned long long* wp = &hbuf[(size_t)(t & 1) * (BATCH * 256) + b * 256 + L];
        do {
            v = __hip_atomic_load(wp, __ATOMIC_RELAXED, __HIP_MEMORY_SCOPE_AGENT);
        } while ((unsigned)(v >> 32) != (unsigned)(t + 1) && --budget > 0);
        unsigned hb = (unsigned)v;

        {   // scatter into LDS chunks
            int p = (KIN / 2) + L;       // recurrent-part pair index
            hv[(p / P) * CH + (p % P)] = hb;
            if constexpr (KIN == 128) {
                if (L < 64) hv[L] = pack2(xf.x, xf.y);
            } else {
                hv[(L >> 7) * CH + (L & 127)] = nv;
            }
        }
        __syncthreads();
        nz_cur = nz_nxt;
    }
}

__global__ void fc_kernel(const float* __restrict__ h1f, const float* __restrict__ fcw,
                          const float* __restrict__ fcb, float* __restrict__ out) {
    const int b = blockIdx.x, tid = threadIdx.x;
    __shared__ float hs[512];
    __shared__ float part[256];
    hs[tid]       = h1f[b * 512 + tid];
    hs[256 + tid] = h1f[b * 512 + 256 + tid];
    __syncthreads();
    const int w = tid & 31, seg = tid >> 5;      // 8 k-segments x 32 outputs
    const float* wr = fcw + w * 512 + seg * 64;
    const float* hr = hs + seg * 64;
    float a = 0.f;
#pragma unroll
    for (int k = 0; k < 64; ++k) a = fmaf(wr[k], hr[k], a);
    part[tid] = a;
    __syncthreads();
    if (tid < 32) {
        float s = fcb[tid];
#pragma unroll
        for (int sgi = 0; sgi < 8; ++sgi) s += part[sgi * 32 + tid];
        out[b * 32 + tid] = s;
    }
}

extern "C" void kernel_launch(void* const* d_in, const int* in_sizes, int n_in,
                              void* d_out, int out_size, void* d_ws, size_t ws_size,
                              hipStream_t stream) {
    const float* x     = (const float*)d_in[0];
    const float* noise = (const float*)d_in[1];
    const float* Wih0  = (const float*)d_in[2];
    const float* Wih1  = (const float*)d_in[3];
    const float* Whh0  = (const float*)d_in[4];
    const float* Whh1  = (const float*)d_in[5];
    const float* bih0  = (const float*)d_in[6];
    const float* bih1  = (const float*)d_in[7];
    const float* bhh0  = (const float*)d_in[8];
    const float* bhh1  = (const float*)d_in[9];
    const float* fcw   = (const float*)d_in[10];
    const float* fcb   = (const float*)d_in[11];
    float* out = (float*)d_out;

    char* ws = (char*)d_ws;
    size_t o = 0;
    unsigned* wp0 = (unsigned*)(ws + o); o += (size_t)N0 * 4;                 // 640 KB
    unsigned* wp1 = (unsigned*)(ws + o); o += (size_t)N1 * 4;                 // 1 MB
    unsigned long long* hb0 = (unsigned long long*)(ws + o); o += (size_t)2 * BATCH * 256 * 8;
    unsigned long long* hb1 = (unsigned long long*)(ws + o); o += (size_t)2 * BATCH * 256 * 8;
    float*    h1f = (float*)(ws + o);    o += (size_t)BATCH * 512 * 4;
    unsigned* seq = (unsigned*)(ws + o); o += (size_t)BATCH * TSTEPS * 256 * 4; // 33.5 MB

    const int initBlocks = (N0 + N1 + 255) / 256;
    init_pack<<<initBlocks, 256, 0, stream>>>(Wih0, Whh0, Wih1, Whh1, wp0, wp1);
    chain_kernel<128, true ><<<512, 256, 0, stream>>>(x, nullptr, seq, wp0, bih0, bhh0,
                                                      noise, hb0, nullptr);
    chain_kernel<512, false><<<512, 256, 0, stream>>>(nullptr, seq, nullptr, wp1, bih1, bhh1,
                                                      noise, hb1, h1f);
    fc_kernel<<<BATCH, 256, 0, stream>>>(h1f, fcw, fcb, out);
}